// Round 1
// baseline (1394.959 us; speedup 1.0000x reference)
//
#include <hip/hip_runtime.h>

#define NDEV 8192
#define NAP  4
#define NSAMP 32768
#define EDD 262144
#define EDA 32768
#define EAD 32768
#define CHUNK 8192  // samples per conv/fc pass (c2 buffer = CHUNK*2048 f32 = 64MB)

// ---------------------------------------------------------------------------
// CSI encoder stage 1: conv1 (2->16, 3x3 SAME, relu) + conv2 (16->32, 3x3 SAME, relu)
// One block = 4 samples, 256 threads.
// ---------------------------------------------------------------------------
__global__ __launch_bounds__(256) void conv_kernel(
    const float* __restrict__ csi,   // chunk base: [CHUNK][8][8][2]
    float* __restrict__ c2,          // [CHUNK][2048]  (oc*64 + f*8 + t)
    const float* __restrict__ w1, const float* __restrict__ b1,
    const float* __restrict__ w2, const float* __restrict__ b2)
{
    __shared__ float sw1[288];
    __shared__ float sb1[16];
    __shared__ float sw2[4608];
    __shared__ float sb2[32];
    __shared__ float inpad[4][2][10][10];
    __shared__ float c1pad[4][16][10][10];
    const int tid = threadIdx.x;

    for (int i = tid; i < 288; i += 256) sw1[i] = w1[i];
    if (tid < 16) sb1[tid] = b1[tid];
    for (int i = tid; i < 4608; i += 256) sw2[i] = w2[i];
    if (tid < 32) sb2[tid] = b2[tid];
    float* ip = &inpad[0][0][0][0];
    for (int i = tid; i < 800; i += 256) ip[i] = 0.f;
    float* cp = &c1pad[0][0][0][0];
    for (int i = tid; i < 6400; i += 256) cp[i] = 0.f;
    __syncthreads();

    const long s0 = (long)blockIdx.x * 4;
    for (int i = tid; i < 512; i += 256) {
        int si = i >> 7, r = i & 127;
        int f = r >> 4, t = (r >> 1) & 7, c = r & 1;
        inpad[si][c][f + 1][t + 1] = csi[s0 * 128 + i];
    }
    __syncthreads();

    // conv1: 4*16*64 = 4096 outputs, 16 per thread
    for (int j = 0; j < 16; ++j) {
        int idx = tid + j * 256;
        int t = idx & 7, f = (idx >> 3) & 7, oc = (idx >> 6) & 15, si = idx >> 10;
        float acc = sb1[oc];
        #pragma unroll
        for (int ic = 0; ic < 2; ++ic)
            #pragma unroll
            for (int df = 0; df < 3; ++df)
                #pragma unroll
                for (int dt = 0; dt < 3; ++dt)
                    acc += inpad[si][ic][f + df][t + dt] * sw1[((oc * 2 + ic) * 3 + df) * 3 + dt];
        c1pad[si][oc][f + 1][t + 1] = fmaxf(acc, 0.f);
    }
    __syncthreads();

    // conv2: thread = (oc group of 4) x (si,f row); 4 oc x 8 t accumulators
    const int ocg = tid >> 5;          // 0..7  -> ocs ocg*4 .. ocg*4+3
    const int row = tid & 31;          // si = row>>3, f = row&7
    const int si = row >> 3, f = row & 7;
    float acc[4][8];
    #pragma unroll
    for (int i = 0; i < 4; ++i) {
        float b = sb2[ocg * 4 + i];
        #pragma unroll
        for (int t = 0; t < 8; ++t) acc[i][t] = b;
    }
    for (int ic = 0; ic < 16; ++ic) {
        float r0[10], r1[10], r2[10];
        #pragma unroll
        for (int u = 0; u < 10; ++u) {
            r0[u] = c1pad[si][ic][f + 0][u];
            r1[u] = c1pad[si][ic][f + 1][u];
            r2[u] = c1pad[si][ic][f + 2][u];
        }
        #pragma unroll
        for (int i = 0; i < 4; ++i) {
            const float* wb = &sw2[((ocg * 4 + i) * 16 + ic) * 9];
            #pragma unroll
            for (int dt = 0; dt < 3; ++dt) {
                float w0 = wb[dt], w1v = wb[3 + dt], w2v = wb[6 + dt];
                #pragma unroll
                for (int t = 0; t < 8; ++t)
                    acc[i][t] += r0[t + dt] * w0 + r1[t + dt] * w1v + r2[t + dt] * w2v;
            }
        }
    }
    #pragma unroll
    for (int i = 0; i < 4; ++i) {
        int oc = ocg * 4 + i;
        #pragma unroll
        for (int t = 0; t < 8; ++t)
            c2[(s0 + si) * 2048 + oc * 64 + f * 8 + t] = fmaxf(acc[i][t], 0.f);
    }
}

// ---------------------------------------------------------------------------
// CSI encoder stage 2: fc GEMM  [CHUNK,2048] @ [2048,64] + bias, relu
// Block: 64-sample M-tile, 256 threads, 4x4 accum per thread.
// ---------------------------------------------------------------------------
__global__ __launch_bounds__(256) void fc_kernel(
    const float* __restrict__ c2, const float* __restrict__ W,
    const float* __restrict__ bias, float* __restrict__ out)
{
    __shared__ float At[64][65];
    __shared__ float Bt[64][64];
    const int tid = threadIdx.x;
    const int m0 = blockIdx.x * 64;
    const int r0 = (tid >> 4) * 4;
    const int c0 = (tid & 15) * 4;
    float acc[4][4] = {{0.f}};

    for (int kc = 0; kc < 2048; kc += 64) {
        __syncthreads();
        for (int s = tid; s < 1024; s += 256) {
            int m = s >> 4, k4 = (s & 15) * 4;
            const float4 v = *(const float4*)&c2[(long)(m0 + m) * 2048 + kc + k4];
            At[m][k4 + 0] = v.x; At[m][k4 + 1] = v.y; At[m][k4 + 2] = v.z; At[m][k4 + 3] = v.w;
        }
        for (int s = tid; s < 1024; s += 256) {
            int k = s >> 4, o4 = (s & 15) * 4;
            *(float4*)&Bt[k][o4] = *(const float4*)&W[(long)(kc + k) * 64 + o4];
        }
        __syncthreads();
        #pragma unroll 8
        for (int k = 0; k < 64; ++k) {
            float4 b = *(const float4*)&Bt[k][c0];
            #pragma unroll
            for (int i = 0; i < 4; ++i) {
                float a = At[r0 + i][k];
                acc[i][0] += a * b.x; acc[i][1] += a * b.y;
                acc[i][2] += a * b.z; acc[i][3] += a * b.w;
            }
        }
    }
    #pragma unroll
    for (int i = 0; i < 4; ++i)
        #pragma unroll
        for (int j = 0; j < 4; ++j)
            out[(long)(m0 + r0 + i) * 64 + c0 + j] = fmaxf(acc[i][j] + bias[c0 + j], 0.f);
}

// ---------------------------------------------------------------------------
// Device encoder: pos_f(16) + csi_f(64) -> merge(80->64), relu. 8 devices/block.
// ---------------------------------------------------------------------------
__global__ __launch_bounds__(256) void dev_enc_kernel(
    const float* __restrict__ dpos, const int* __restrict__ pkts,
    const float* __restrict__ emb,
    const float* __restrict__ Wp, const float* __restrict__ bp,
    const float* __restrict__ Wc, const float* __restrict__ bc,
    const float* __restrict__ Wm, const float* __restrict__ bm,
    float* __restrict__ hdev)
{
    __shared__ float se[8][256];
    __shared__ float sposf[8][16];
    __shared__ float scsif[8][64];
    const int tid = threadIdx.x;
    const int d0 = blockIdx.x * 8;
    for (int i = tid; i < 2048; i += 256) se[i >> 8][i & 255] = emb[(long)d0 * 256 + i];
    __syncthreads();
    const int o = tid & 63, g = tid >> 6;
    for (int half = 0; half < 2; ++half) {
        int dl = half * 4 + g;
        float a = bc[o];
        for (int k = 0; k < 256; ++k) a += se[dl][k] * Wc[k * 64 + o];
        scsif[dl][o] = fmaxf(a, 0.f);
        if (o < 16) {
            int d = d0 + dl;
            float px = dpos[d * 2], py = dpos[d * 2 + 1], pk = (float)pkts[d];
            float v = bp[o] + px * Wp[o] + py * Wp[16 + o] + pk * Wp[32 + o];
            sposf[dl][o] = fmaxf(v, 0.f);
        }
    }
    __syncthreads();
    for (int half = 0; half < 2; ++half) {
        int dl = half * 4 + g;
        float h = bm[o];
        #pragma unroll
        for (int j = 0; j < 16; ++j) h += sposf[dl][j] * Wm[j * 64 + o];
        #pragma unroll 8
        for (int j = 0; j < 64; ++j) h += scsif[dl][j] * Wm[(16 + j) * 64 + o];
        hdev[(long)(d0 + dl) * 64 + o] = fmaxf(h, 0.f);
    }
}

__global__ void ap_enc_kernel(const float* __restrict__ appos,
                              const float* __restrict__ W, const float* __restrict__ b,
                              float* __restrict__ hap)
{
    int tid = threadIdx.x;  // 256 = 4 aps x 64
    int a = tid >> 6, o = tid & 63;
    float v = b[o] + appos[a * 2] * W[o] + appos[a * 2 + 1] * W[64 + o];
    hap[tid] = fmaxf(v, 0.f);
}

// ---------------------------------------------------------------------------
// Degree histograms (float counts). Grid = EDD/256.
// ---------------------------------------------------------------------------
__global__ __launch_bounds__(256) void degrees_kernel(
    const int* __restrict__ dd_src, const int* __restrict__ dd_dst,
    const int* __restrict__ da_src, const int* __restrict__ da_dst,
    const int* __restrict__ ad_src, const int* __restrict__ ad_dst,
    float* deg_dd_out, float* deg_dd_in, float* deg_da_out,
    float* deg_da_in, float* deg_ad_out, float* deg_ad_in)
{
    __shared__ float s4[8];  // [0..3] da_in, [4..7] ad_out
    const int tid = threadIdx.x;
    if (tid < 8) s4[tid] = 0.f;
    __syncthreads();
    const int gid = blockIdx.x * 256 + tid;
    atomicAdd(&deg_dd_out[dd_src[gid]], 1.f);
    atomicAdd(&deg_dd_in[dd_dst[gid]], 1.f);
    if (gid < EDA) {
        atomicAdd(&deg_da_out[da_src[gid]], 1.f);
        atomicAdd(&s4[da_dst[gid]], 1.f);
        atomicAdd(&s4[4 + ad_src[gid]], 1.f);
        atomicAdd(&deg_ad_in[ad_dst[gid]], 1.f);
    }
    __syncthreads();
    if (tid < 4 && s4[tid] != 0.f) atomicAdd(&deg_da_in[tid], s4[tid]);
    if (tid >= 4 && tid < 8 && s4[tid] != 0.f) atomicAdd(&deg_ad_out[tid - 4], s4[tid]);
}

// ---------------------------------------------------------------------------
// Edge scatter-sum: agg[dst] += x[src] * rsqrt(max(deg_out[src],1)).
// One wave per edge (64 feature lanes). Grid = E/4 blocks.
// ---------------------------------------------------------------------------
__global__ __launch_bounds__(256) void scatter_kernel(
    const int* __restrict__ src, const int* __restrict__ dst,
    const float* __restrict__ x, const float* __restrict__ deg_out,
    float* __restrict__ agg)
{
    const long gid = (long)blockIdx.x * 256 + threadIdx.x;
    const int e = (int)(gid >> 6), f = (int)(gid & 63);
    const int s = src[e], d = dst[e];
    const float sc = rsqrtf(fmaxf(deg_out[s], 1.f));
    atomicAdd(&agg[(long)d * 64 + f], x[(long)s * 64 + f] * sc);
}

// da relation: only 4 destinations -> LDS block reduction then 256 atomics/block.
__global__ __launch_bounds__(256) void da_reduce_kernel(
    const int* __restrict__ src, const int* __restrict__ dst,
    const float* __restrict__ x, const float* __restrict__ deg_out,
    float* __restrict__ agg /* [4][64] */)
{
    __shared__ float sacc[4][64];
    const int tid = threadIdx.x;
    if (tid < 256) (&sacc[0][0])[tid] = 0.f;
    __syncthreads();
    const int f = tid & 63;
    const int base = blockIdx.x * 128;
    for (int e = base + (tid >> 6); e < base + 128; e += 4) {
        int s = src[e], d = dst[e];
        float sc = rsqrtf(fmaxf(deg_out[s], 1.f));
        atomicAdd(&sacc[d][f], x[(long)s * 64 + f] * sc);
    }
    __syncthreads();
    float v = (&sacc[0][0])[tid];
    if (v != 0.f) atomicAdd(&agg[tid], v);
}

// ---------------------------------------------------------------------------
// Combine two relations into device features:
// out = relu(r1*(agg1@W1) + r2*(agg2@W2) + b1 + b2); 4 devices/block.
// ---------------------------------------------------------------------------
__global__ __launch_bounds__(256) void combine_hd_kernel(
    const float* __restrict__ agg1, const float* __restrict__ degin1,
    const float* __restrict__ W1, const float* __restrict__ b1,
    const float* __restrict__ agg2, const float* __restrict__ degin2,
    const float* __restrict__ W2, const float* __restrict__ b2,
    float* __restrict__ out)
{
    __shared__ float sW1[64][64];
    __shared__ float sW2[64][64];
    __shared__ float sa1[4][64];
    __shared__ float sa2[4][64];
    const int tid = threadIdx.x;
    for (int i = tid; i < 4096; i += 256) { sW1[i >> 6][i & 63] = W1[i]; sW2[i >> 6][i & 63] = W2[i]; }
    const int n0 = blockIdx.x * 4;
    (&sa1[0][0])[tid] = agg1[(long)n0 * 64 + tid];
    (&sa2[0][0])[tid] = agg2[(long)n0 * 64 + tid];
    __syncthreads();
    const int o = tid & 63, dl = tid >> 6;
    const int n = n0 + dl;
    float acc1 = 0.f, acc2 = 0.f;
    #pragma unroll 8
    for (int k = 0; k < 64; ++k) {
        acc1 += sa1[dl][k] * sW1[k][o];
        acc2 += sa2[dl][k] * sW2[k][o];
    }
    float r1 = rsqrtf(fmaxf(degin1[n], 1.f));
    float r2 = rsqrtf(fmaxf(degin2[n], 1.f));
    out[(long)n * 64 + o] = fmaxf(acc1 * r1 + acc2 * r2 + b1[o] + b2[o], 0.f);
}

__global__ void combine_ha_kernel(const float* __restrict__ agg, const float* __restrict__ degin,
                                  const float* __restrict__ W, const float* __restrict__ b,
                                  float* __restrict__ out /* [4][64] */)
{
    const int tid = threadIdx.x;  // 256
    const int o = tid & 63, a = tid >> 6;
    float acc = 0.f;
    for (int k = 0; k < 64; ++k) acc += agg[a * 64 + k] * W[k * 64 + o];
    float r = rsqrtf(fmaxf(degin[a], 1.f));
    out[tid] = fmaxf(acc * r + b[o], 0.f);
}

// ---------------------------------------------------------------------------
// Head: t1 = relu(hd2@W1+b1); logits = t1@W2+b2 -> d_out logits region.
// ---------------------------------------------------------------------------
__global__ __launch_bounds__(256) void head_kernel(
    const float* __restrict__ hd2,
    const float* __restrict__ W1, const float* __restrict__ b1,
    const float* __restrict__ W2, const float* __restrict__ b2,
    float* __restrict__ logits_out)
{
    __shared__ float sW1[64][64];
    __shared__ float sW2[64][32];
    __shared__ float sh[4][64];
    __shared__ float st[4][64];
    const int tid = threadIdx.x;
    for (int i = tid; i < 4096; i += 256) sW1[i >> 6][i & 63] = W1[i];
    for (int i = tid; i < 2048; i += 256) sW2[i >> 5][i & 31] = W2[i];
    const int n0 = blockIdx.x * 4;
    (&sh[0][0])[tid] = hd2[(long)n0 * 64 + tid];
    __syncthreads();
    const int o = tid & 63, dl = tid >> 6;
    float acc = b1[o];
    #pragma unroll 8
    for (int k = 0; k < 64; ++k) acc += sh[dl][k] * sW1[k][o];
    st[dl][o] = fmaxf(acc, 0.f);
    __syncthreads();
    if (tid < 128) {
        int j = tid & 31, d2 = tid >> 5;
        float a2 = b2[j];
        #pragma unroll 8
        for (int k = 0; k < 64; ++k) a2 += st[d2][k] * sW2[k][j];
        logits_out[(long)(n0 + d2) * 32 + j] = a2;
    }
}

// ---------------------------------------------------------------------------
// Softmax stats per (a,t) column j: max, first-argmax, sum(exp(x-max)).
// ---------------------------------------------------------------------------
__global__ __launch_bounds__(256) void softmax_stats_kernel(
    const float* __restrict__ logits,
    float* __restrict__ smax, int* __restrict__ sargm, float* __restrict__ ssum)
{
    __shared__ float smx[256];
    __shared__ int sid[256];
    __shared__ float ssm[256];
    const int j = blockIdx.x;
    const int tid = threadIdx.x;
    float best = -__builtin_inff(); int bid = 0x7fffffff;
    for (int n = tid; n < NDEV; n += 256) {
        float v = logits[n * 32 + j];
        if (v > best) { best = v; bid = n; }
    }
    smx[tid] = best; sid[tid] = bid;
    __syncthreads();
    for (int s = 128; s > 0; s >>= 1) {
        if (tid < s) {
            float v2 = smx[tid + s]; int i2 = sid[tid + s];
            if (v2 > smx[tid] || (v2 == smx[tid] && i2 < sid[tid])) { smx[tid] = v2; sid[tid] = i2; }
        }
        __syncthreads();
    }
    const float mx = smx[0];
    float part = 0.f;
    for (int n = tid; n < NDEV; n += 256) part += expf(logits[n * 32 + j] - mx);
    ssm[tid] = part;
    __syncthreads();
    for (int s = 128; s > 0; s >>= 1) {
        if (tid < s) ssm[tid] += ssm[tid + s];
        __syncthreads();
    }
    if (tid == 0) { smax[j] = mx; sargm[j] = sid[0]; ssum[j] = ssm[0]; }
}

__global__ __launch_bounds__(256) void final_kernel(
    const float* __restrict__ logits, const float* __restrict__ smax,
    const int* __restrict__ sargm, const float* __restrict__ ssum,
    float* __restrict__ hard, float* __restrict__ soft)
{
    const int gid = blockIdx.x * 256 + threadIdx.x;  // 65536 (n,t) pairs
    const int n = gid >> 3, t = gid & 7;
    float s = 0.f; int h = 0;
    #pragma unroll
    for (int a = 0; a < 4; ++a) {
        int j = t * 4 + a;
        s += expf(logits[n * 32 + j] - smax[j]) / ssum[j];
        h |= (sargm[j] == n) ? 1 : 0;
    }
    hard[gid] = (float)h;
    soft[gid] = s;
}

// ---------------------------------------------------------------------------
extern "C" void kernel_launch(void* const* d_in, const int* in_sizes, int n_in,
                              void* d_out, int out_size, void* d_ws, size_t ws_size,
                              hipStream_t stream)
{
    const float* device_pos = (const float*)d_in[0];
    const float* ap_pos     = (const float*)d_in[1];
    const float* csi        = (const float*)d_in[2];
    const int*   node_pk    = (const int*)d_in[3];
    const int* dd_src = (const int*)d_in[4];
    const int* dd_dst = (const int*)d_in[5];
    const int* da_src = (const int*)d_in[6];
    const int* da_dst = (const int*)d_in[7];
    const int* ad_src = (const int*)d_in[8];
    const int* ad_dst = (const int*)d_in[9];
    const float* w1  = (const float*)d_in[10]; const float* b1  = (const float*)d_in[11];
    const float* w2  = (const float*)d_in[12]; const float* b2  = (const float*)d_in[13];
    const float* fcW = (const float*)d_in[14]; const float* fcb = (const float*)d_in[15];
    const float* Wp  = (const float*)d_in[16]; const float* bp  = (const float*)d_in[17];
    const float* Wc  = (const float*)d_in[18]; const float* bc  = (const float*)d_in[19];
    const float* Wm  = (const float*)d_in[20]; const float* bm  = (const float*)d_in[21];
    const float* Wap = (const float*)d_in[22]; const float* bap = (const float*)d_in[23];
    const float* g1ddW = (const float*)d_in[24]; const float* g1ddb = (const float*)d_in[25];
    const float* g1daW = (const float*)d_in[26]; const float* g1dab = (const float*)d_in[27];
    const float* g1adW = (const float*)d_in[28]; const float* g1adb = (const float*)d_in[29];
    const float* g2ddW = (const float*)d_in[30]; const float* g2ddb = (const float*)d_in[31];
    /* g2da (32,33) unused in the reference forward */
    const float* g2adW = (const float*)d_in[34]; const float* g2adb = (const float*)d_in[35];
    const float* a1W = (const float*)d_in[36]; const float* a1b = (const float*)d_in[37];
    const float* a2W = (const float*)d_in[38]; const float* a2b = (const float*)d_in[39];

    float* ws = (float*)d_ws;
    // ws layout (floats)
    size_t o_c2     = 0;                              // CHUNK*2048 = 16,777,216
    size_t o_emb    = o_c2 + (size_t)CHUNK * 2048;    // 32768*64  = 2,097,152
    size_t o_hdev   = o_emb + (size_t)NSAMP * 64;     // 8192*64
    size_t o_hap    = o_hdev + (size_t)NDEV * 64;     // 256
    size_t o_zero   = o_hap + 256;
    size_t o_ddo    = o_zero;                 // 8192
    size_t o_ddi    = o_ddo + NDEV;           // 8192
    size_t o_dao    = o_ddi + NDEV;           // 8192
    size_t o_dai    = o_dao + NDEV;           // 8
    size_t o_ado    = o_dai + 8;              // 8
    size_t o_adi    = o_ado + 8;              // 8192
    size_t o_aggdd1 = o_adi + NDEV;           // 8192*64
    size_t o_aggad1 = o_aggdd1 + (size_t)NDEV * 64;
    size_t o_aggda1 = o_aggad1 + (size_t)NDEV * 64;   // 256
    size_t o_aggdd2 = o_aggda1 + 256;
    size_t o_aggad2 = o_aggdd2 + (size_t)NDEV * 64;
    size_t o_zend   = o_aggad2 + (size_t)NDEV * 64;
    size_t o_hd1    = o_zend;
    size_t o_ha1    = o_hd1 + (size_t)NDEV * 64;      // 256
    size_t o_hd2    = o_ha1 + 256;
    size_t o_smax   = o_hd2 + (size_t)NDEV * 64;      // 32
    size_t o_ssum   = o_smax + 32;                    // 32
    size_t o_sargm  = o_ssum + 32;                    // 32 ints

    float* out = (float*)d_out;
    float* out_hard   = out;                 // [8192][8]
    float* out_logits = out + 65536;         // [8192][8][4] == [8192][32]
    float* out_soft   = out + 65536 + 262144;

    // zero degree + agg buffers
    hipMemsetAsync((void*)(ws + o_zero), 0, (o_zend - o_zero) * sizeof(float), stream);

    // CSI encoder in 4 chunks of 8192 samples (c2 buffer reused)
    for (int c = 0; c < 4; ++c) {
        const float* csi_c = csi + (size_t)c * CHUNK * 128;
        float* emb_c = ws + o_emb + (size_t)c * CHUNK * 64;
        conv_kernel<<<CHUNK / 4, 256, 0, stream>>>(csi_c, ws + o_c2, w1, b1, w2, b2);
        fc_kernel<<<CHUNK / 64, 256, 0, stream>>>(ws + o_c2, fcW, fcb, emb_c);
    }

    dev_enc_kernel<<<NDEV / 8, 256, 0, stream>>>(device_pos, node_pk, ws + o_emb,
                                                 Wp, bp, Wc, bc, Wm, bm, ws + o_hdev);
    ap_enc_kernel<<<1, 256, 0, stream>>>(ap_pos, Wap, bap, ws + o_hap);

    degrees_kernel<<<EDD / 256, 256, 0, stream>>>(dd_src, dd_dst, da_src, da_dst, ad_src, ad_dst,
                                                  ws + o_ddo, ws + o_ddi, ws + o_dao,
                                                  ws + o_dai, ws + o_ado, ws + o_adi);

    // layer 1
    scatter_kernel<<<EDD / 4, 256, 0, stream>>>(dd_src, dd_dst, ws + o_hdev, ws + o_ddo, ws + o_aggdd1);
    scatter_kernel<<<EAD / 4, 256, 0, stream>>>(ad_src, ad_dst, ws + o_hap, ws + o_ado, ws + o_aggad1);
    da_reduce_kernel<<<EDA / 128, 256, 0, stream>>>(da_src, da_dst, ws + o_hdev, ws + o_dao, ws + o_aggda1);
    combine_hd_kernel<<<NDEV / 4, 256, 0, stream>>>(ws + o_aggdd1, ws + o_ddi, g1ddW, g1ddb,
                                                    ws + o_aggad1, ws + o_adi, g1adW, g1adb,
                                                    ws + o_hd1);
    combine_ha_kernel<<<1, 256, 0, stream>>>(ws + o_aggda1, ws + o_dai, g1daW, g1dab, ws + o_ha1);

    // layer 2 (hd2 only; g2_da unused in reference forward)
    scatter_kernel<<<EDD / 4, 256, 0, stream>>>(dd_src, dd_dst, ws + o_hd1, ws + o_ddo, ws + o_aggdd2);
    scatter_kernel<<<EAD / 4, 256, 0, stream>>>(ad_src, ad_dst, ws + o_ha1, ws + o_ado, ws + o_aggad2);
    combine_hd_kernel<<<NDEV / 4, 256, 0, stream>>>(ws + o_aggdd2, ws + o_ddi, g2ddW, g2ddb,
                                                    ws + o_aggad2, ws + o_adi, g2adW, g2adb,
                                                    ws + o_hd2);

    head_kernel<<<NDEV / 4, 256, 0, stream>>>(ws + o_hd2, a1W, a1b, a2W, a2b, out_logits);

    softmax_stats_kernel<<<32, 256, 0, stream>>>(out_logits, ws + o_smax,
                                                 (int*)(ws + o_sargm), ws + o_ssum);
    final_kernel<<<65536 / 256, 256, 0, stream>>>(out_logits, ws + o_smax,
                                                  (int*)(ws + o_sargm), ws + o_ssum,
                                                  out_hard, out_soft);
    (void)in_sizes; (void)n_in; (void)out_size; (void)ws_size; (void)node_pk;
}

// Round 2
// 1020.154 us; speedup vs baseline: 1.3674x; 1.3674x over previous
//
#include <hip/hip_runtime.h>

#define NDEV 8192
#define NAP  4
#define NSAMP 32768
#define EDD 262144
#define EDA 32768
#define EAD 32768
#define CHUNK 8192
#define KC 128

// ---------------------------------------------------------------------------
// CSI encoder stage 1: conv1 (2->16) + conv2 (16->32), 3x3 SAME, relu.
// One block = 4 samples, 256 threads.
// ---------------------------------------------------------------------------
__global__ __launch_bounds__(256) void conv_kernel(
    const float* __restrict__ csi,
    float* __restrict__ c2,          // [CHUNK][2048]  (oc*64 + f*8 + t)
    const float* __restrict__ w1, const float* __restrict__ b1,
    const float* __restrict__ w2, const float* __restrict__ b2)
{
    __shared__ float sw1[288];
    __shared__ float sb1[16];
    __shared__ float sw2[4608];
    __shared__ float sb2[32];
    __shared__ float inpad[4][2][10][10];
    __shared__ float c1pad[4][16][10][10];
    const int tid = threadIdx.x;

    for (int i = tid; i < 288; i += 256) sw1[i] = w1[i];
    if (tid < 16) sb1[tid] = b1[tid];
    for (int i = tid; i < 4608; i += 256) sw2[i] = w2[i];
    if (tid < 32) sb2[tid] = b2[tid];
    float* ip = &inpad[0][0][0][0];
    for (int i = tid; i < 800; i += 256) ip[i] = 0.f;
    float* cp = &c1pad[0][0][0][0];
    for (int i = tid; i < 6400; i += 256) cp[i] = 0.f;
    __syncthreads();

    const long s0 = (long)blockIdx.x * 4;
    for (int i = tid; i < 512; i += 256) {
        int si = i >> 7, r = i & 127;
        int f = r >> 4, t = (r >> 1) & 7, c = r & 1;
        inpad[si][c][f + 1][t + 1] = csi[s0 * 128 + i];
    }
    __syncthreads();

    for (int j = 0; j < 16; ++j) {
        int idx = tid + j * 256;
        int t = idx & 7, f = (idx >> 3) & 7, oc = (idx >> 6) & 15, si = idx >> 10;
        float acc = sb1[oc];
        #pragma unroll
        for (int ic = 0; ic < 2; ++ic)
            #pragma unroll
            for (int df = 0; df < 3; ++df)
                #pragma unroll
                for (int dt = 0; dt < 3; ++dt)
                    acc += inpad[si][ic][f + df][t + dt] * sw1[((oc * 2 + ic) * 3 + df) * 3 + dt];
        c1pad[si][oc][f + 1][t + 1] = fmaxf(acc, 0.f);
    }
    __syncthreads();

    const int ocg = tid >> 5;
    const int row = tid & 31;
    const int si = row >> 3, f = row & 7;
    float acc[4][8];
    #pragma unroll
    for (int i = 0; i < 4; ++i) {
        float b = sb2[ocg * 4 + i];
        #pragma unroll
        for (int t = 0; t < 8; ++t) acc[i][t] = b;
    }
    for (int ic = 0; ic < 16; ++ic) {
        float r0[10], r1[10], r2[10];
        #pragma unroll
        for (int u = 0; u < 10; ++u) {
            r0[u] = c1pad[si][ic][f + 0][u];
            r1[u] = c1pad[si][ic][f + 1][u];
            r2[u] = c1pad[si][ic][f + 2][u];
        }
        #pragma unroll
        for (int i = 0; i < 4; ++i) {
            const float* wb = &sw2[((ocg * 4 + i) * 16 + ic) * 9];
            #pragma unroll
            for (int dt = 0; dt < 3; ++dt) {
                float w0 = wb[dt], w1v = wb[3 + dt], w2v = wb[6 + dt];
                #pragma unroll
                for (int t = 0; t < 8; ++t)
                    acc[i][t] += r0[t + dt] * w0 + r1[t + dt] * w1v + r2[t + dt] * w2v;
            }
        }
    }
    #pragma unroll
    for (int i = 0; i < 4; ++i) {
        int oc = ocg * 4 + i;
        #pragma unroll
        for (int t = 0; t < 8; ++t)
            c2[(s0 + si) * 2048 + oc * 64 + f * 8 + t] = fmaxf(acc[i][t], 0.f);
    }
}

// ---------------------------------------------------------------------------
// CSI encoder stage 2: [CHUNK,2048] @ [2048,64] + bias, relu.
// M-tile 16, K split 4-ways across waves, 4x4 microtile. Grid = CHUNK/16.
// ---------------------------------------------------------------------------
__global__ __launch_bounds__(256) void fc16_kernel(
    const float* __restrict__ c2, const float* __restrict__ W,
    const float* __restrict__ bias, float* __restrict__ out)
{
    __shared__ __align__(16) float smem[KC * 16 + KC * 64];  // As | Ws (red aliases)
    float* As = smem;            // [KC][16] k-major
    float* Ws = smem + KC * 16;  // [KC][64]
    const int tid = threadIdx.x;
    const long m0g = (long)blockIdx.x * 16;
    const int ks = tid >> 6;          // wave id = K split
    const int lane = tid & 63;
    const int m0 = (lane >> 4) * 4;
    const int o0 = (lane & 15) * 4;
    float acc[4][4] = {{0.f}};

    for (int kc = 0; kc < 2048; kc += KC) {
        __syncthreads();
        #pragma unroll
        for (int i = 0; i < 2; ++i) {
            int idx = tid + i * 256;          // 512 float4 of A
            int m = idx >> 5, kq = idx & 31;
            float4 v = *(const float4*)&c2[(m0g + m) * 2048 + kc + kq * 4];
            As[(kq * 4 + 0) * 16 + m] = v.x;
            As[(kq * 4 + 1) * 16 + m] = v.y;
            As[(kq * 4 + 2) * 16 + m] = v.z;
            As[(kq * 4 + 3) * 16 + m] = v.w;
        }
        #pragma unroll
        for (int i = 0; i < 8; ++i) {
            int idx = tid + i * 256;          // 2048 float4 of W
            int k = idx >> 4, oq = idx & 15;
            *(float4*)&Ws[k * 64 + oq * 4] = *(const float4*)&W[(long)(kc + k) * 64 + oq * 4];
        }
        __syncthreads();
        const int kb = ks * 32;
        #pragma unroll 8
        for (int kk = 0; kk < 32; ++kk) {
            float4 a4 = *(const float4*)&As[(kb + kk) * 16 + m0];
            float4 w4 = *(const float4*)&Ws[(kb + kk) * 64 + o0];
            float av[4] = {a4.x, a4.y, a4.z, a4.w};
            float wv[4] = {w4.x, w4.y, w4.z, w4.w};
            #pragma unroll
            for (int i = 0; i < 4; ++i)
                #pragma unroll
                for (int j = 0; j < 4; ++j)
                    acc[i][j] += av[i] * wv[j];
        }
    }
    __syncthreads();
    float* red = smem;  // [4][16][64]
    #pragma unroll
    for (int i = 0; i < 4; ++i)
        #pragma unroll
        for (int j = 0; j < 4; ++j)
            red[(ks * 16 + m0 + i) * 64 + o0 + j] = acc[i][j];
    __syncthreads();
    {
        int m = tid >> 4, oq = tid & 15;
        float4 r0 = *(float4*)&red[(0 * 16 + m) * 64 + oq * 4];
        float4 r1 = *(float4*)&red[(1 * 16 + m) * 64 + oq * 4];
        float4 r2 = *(float4*)&red[(2 * 16 + m) * 64 + oq * 4];
        float4 r3 = *(float4*)&red[(3 * 16 + m) * 64 + oq * 4];
        const float4 b4 = *(const float4*)&bias[oq * 4];
        float4 o4;
        o4.x = fmaxf(r0.x + r1.x + r2.x + r3.x + b4.x, 0.f);
        o4.y = fmaxf(r0.y + r1.y + r2.y + r3.y + b4.y, 0.f);
        o4.z = fmaxf(r0.z + r1.z + r2.z + r3.z + b4.z, 0.f);
        o4.w = fmaxf(r0.w + r1.w + r2.w + r3.w + b4.w, 0.f);
        *(float4*)&out[(m0g + m) * 64 + oq * 4] = o4;
    }
}

// ---------------------------------------------------------------------------
// Device encoder (unchanged).
// ---------------------------------------------------------------------------
__global__ __launch_bounds__(256) void dev_enc_kernel(
    const float* __restrict__ dpos, const int* __restrict__ pkts,
    const float* __restrict__ emb,
    const float* __restrict__ Wp, const float* __restrict__ bp,
    const float* __restrict__ Wc, const float* __restrict__ bc,
    const float* __restrict__ Wm, const float* __restrict__ bm,
    float* __restrict__ hdev)
{
    __shared__ float se[8][256];
    __shared__ float sposf[8][16];
    __shared__ float scsif[8][64];
    const int tid = threadIdx.x;
    const int d0 = blockIdx.x * 8;
    for (int i = tid; i < 2048; i += 256) se[i >> 8][i & 255] = emb[(long)d0 * 256 + i];
    __syncthreads();
    const int o = tid & 63, g = tid >> 6;
    for (int half = 0; half < 2; ++half) {
        int dl = half * 4 + g;
        float a = bc[o];
        for (int k = 0; k < 256; ++k) a += se[dl][k] * Wc[k * 64 + o];
        scsif[dl][o] = fmaxf(a, 0.f);
        if (o < 16) {
            int d = d0 + dl;
            float px = dpos[d * 2], py = dpos[d * 2 + 1], pk = (float)pkts[d];
            float v = bp[o] + px * Wp[o] + py * Wp[16 + o] + pk * Wp[32 + o];
            sposf[dl][o] = fmaxf(v, 0.f);
        }
    }
    __syncthreads();
    for (int half = 0; half < 2; ++half) {
        int dl = half * 4 + g;
        float h = bm[o];
        #pragma unroll
        for (int j = 0; j < 16; ++j) h += sposf[dl][j] * Wm[j * 64 + o];
        #pragma unroll 8
        for (int j = 0; j < 64; ++j) h += scsif[dl][j] * Wm[(16 + j) * 64 + o];
        hdev[(long)(d0 + dl) * 64 + o] = fmaxf(h, 0.f);
    }
}

__global__ void ap_enc_kernel(const float* __restrict__ appos,
                              const float* __restrict__ W, const float* __restrict__ b,
                              float* __restrict__ hap)
{
    int tid = threadIdx.x;
    int a = tid >> 6, o = tid & 63;
    float v = b[o] + appos[a * 2] * W[o] + appos[a * 2 + 1] * W[64 + o];
    hap[tid] = fmaxf(v, 0.f);
}

// ---------------------------------------------------------------------------
// Integer degree histograms. deg_small: [0..7]=da_in, [8..15]=ad_out.
// ---------------------------------------------------------------------------
__global__ __launch_bounds__(256) void degrees_kernel(
    const int* __restrict__ dd_src, const int* __restrict__ dd_dst,
    const int* __restrict__ da_src, const int* __restrict__ da_dst,
    const int* __restrict__ ad_src, const int* __restrict__ ad_dst,
    int* deg_dd_out, int* deg_dd_in, int* deg_da_out, int* deg_ad_in, int* deg_small)
{
    __shared__ int s4[16];
    const int tid = threadIdx.x;
    if (tid < 16) s4[tid] = 0;
    __syncthreads();
    const int gid = blockIdx.x * 256 + tid;
    atomicAdd(&deg_dd_out[dd_src[gid]], 1);
    atomicAdd(&deg_dd_in[dd_dst[gid]], 1);
    if (gid < EDA) {
        atomicAdd(&deg_da_out[da_src[gid]], 1);
        atomicAdd(&s4[da_dst[gid]], 1);
        atomicAdd(&s4[8 + ad_src[gid]], 1);
        atomicAdd(&deg_ad_in[ad_dst[gid]], 1);
    }
    __syncthreads();
    if (tid < 16 && s4[tid] != 0) atomicAdd(&deg_small[tid], s4[tid]);
}

// ---------------------------------------------------------------------------
// Exclusive scan of 8192 ints; writes row_start and cursor. Block 0: A, 1: B.
// ---------------------------------------------------------------------------
__global__ __launch_bounds__(1024) void scan_kernel(
    const int* __restrict__ degA, int* rsA, int* curA,
    const int* __restrict__ degB, int* rsB, int* curB)
{
    const int* deg = blockIdx.x ? degB : degA;
    int* rs = blockIdx.x ? rsB : rsA;
    int* cur = blockIdx.x ? curB : curA;
    __shared__ int sd[1024];
    const int tid = threadIdx.x;
    const int base = tid * 8;
    int v[8]; int s = 0;
    #pragma unroll
    for (int j = 0; j < 8; ++j) { v[j] = deg[base + j]; s += v[j]; }
    sd[tid] = s;
    __syncthreads();
    for (int off = 1; off < 1024; off <<= 1) {
        int t = (tid >= off) ? sd[tid - off] : 0;
        __syncthreads();
        sd[tid] += t;
        __syncthreads();
    }
    int ex = sd[tid] - s;
    #pragma unroll
    for (int j = 0; j < 8; ++j) { rs[base + j] = ex; cur[base + j] = ex; ex += v[j]; }
}

// Bucket edges by dst using cursor (a copy of row_start).
__global__ __launch_bounds__(256) void reorder_kernel(
    const int* __restrict__ src, const int* __restrict__ dst,
    int* __restrict__ cursor, int* __restrict__ ssrc, int nE)
{
    int e = blockIdx.x * 256 + threadIdx.x;
    if (e < nE) {
        int pos = atomicAdd(&cursor[dst[e]], 1);
        ssrc[pos] = src[e];
    }
}

// ---------------------------------------------------------------------------
// CSR gather: agg[d] = rsqrt(deg_in[d]) * sum_{e in CSR(d)} x[src_e]*rsqrt(deg_out[src_e]).
// One block per dst, no atomics.
// ---------------------------------------------------------------------------
__global__ __launch_bounds__(256) void gather_kernel(
    const int* __restrict__ row_start, const int* __restrict__ deg_in,
    const int* __restrict__ ssrc, const float* __restrict__ x,
    const int* __restrict__ deg_out, float* __restrict__ agg)
{
    __shared__ float part[4][64];
    const int d = blockIdx.x;
    const int tid = threadIdx.x;
    const int f = tid & 63, w = tid >> 6;
    const int start = row_start[d], len = deg_in[d];
    float acc = 0.f;
    for (int j = w; j < len; j += 4) {
        int s = ssrc[start + j];
        float sc = rsqrtf(fmaxf((float)deg_out[s], 1.f));
        acc += x[(long)s * 64 + f] * sc;
    }
    part[w][f] = acc;
    __syncthreads();
    if (tid < 64) {
        float v = part[0][f] + part[1][f] + part[2][f] + part[3][f];
        float r = rsqrtf(fmaxf((float)len, 1.f));
        agg[(long)d * 64 + f] = v * r;
    }
}

// da relation: 4 dsts, LDS block reduction then global atomics (raw sum).
__global__ __launch_bounds__(256) void da_reduce_kernel(
    const int* __restrict__ src, const int* __restrict__ dst,
    const float* __restrict__ x, const int* __restrict__ deg_out,
    float* __restrict__ agg /* [4][64] */)
{
    __shared__ float sacc[4][64];
    const int tid = threadIdx.x;
    (&sacc[0][0])[tid] = 0.f;
    __syncthreads();
    const int f = tid & 63;
    const int base = blockIdx.x * 128;
    for (int e = base + (tid >> 6); e < base + 128; e += 4) {
        int s = src[e], d = dst[e];
        float sc = rsqrtf(fmaxf((float)deg_out[s], 1.f));
        atomicAdd(&sacc[d][f], x[(long)s * 64 + f] * sc);
    }
    __syncthreads();
    float v = (&sacc[0][0])[tid];
    if (v != 0.f) atomicAdd(&agg[tid], v);
}

// ---------------------------------------------------------------------------
// out = relu(agg1@W1 + agg2@W2 + b1 + b2); aggs pre-normalized. 4 devices/block.
// ---------------------------------------------------------------------------
__global__ __launch_bounds__(256) void combine_hd_kernel(
    const float* __restrict__ agg1, const float* __restrict__ W1, const float* __restrict__ b1,
    const float* __restrict__ agg2, const float* __restrict__ W2, const float* __restrict__ b2,
    float* __restrict__ out)
{
    __shared__ float sW1[64][64];
    __shared__ float sW2[64][64];
    __shared__ float sa1[4][64];
    __shared__ float sa2[4][64];
    const int tid = threadIdx.x;
    for (int i = tid; i < 4096; i += 256) { sW1[i >> 6][i & 63] = W1[i]; sW2[i >> 6][i & 63] = W2[i]; }
    const int n0 = blockIdx.x * 4;
    (&sa1[0][0])[tid] = agg1[(long)n0 * 64 + tid];
    (&sa2[0][0])[tid] = agg2[(long)n0 * 64 + tid];
    __syncthreads();
    const int o = tid & 63, dl = tid >> 6;
    float acc1 = 0.f, acc2 = 0.f;
    #pragma unroll 8
    for (int k = 0; k < 64; ++k) {
        acc1 += sa1[dl][k] * sW1[k][o];
        acc2 += sa2[dl][k] * sW2[k][o];
    }
    out[(long)(n0 + dl) * 64 + o] = fmaxf(acc1 + acc2 + b1[o] + b2[o], 0.f);
}

__global__ void combine_ha_kernel(const float* __restrict__ agg, const int* __restrict__ degin,
                                  const float* __restrict__ W, const float* __restrict__ b,
                                  float* __restrict__ out /* [4][64] */)
{
    const int tid = threadIdx.x;
    const int o = tid & 63, a = tid >> 6;
    float acc = 0.f;
    for (int k = 0; k < 64; ++k) acc += agg[a * 64 + k] * W[k * 64 + o];
    float r = rsqrtf(fmaxf((float)degin[a], 1.f));
    out[tid] = fmaxf(acc * r + b[o], 0.f);
}

// ---------------------------------------------------------------------------
// Head (unchanged).
// ---------------------------------------------------------------------------
__global__ __launch_bounds__(256) void head_kernel(
    const float* __restrict__ hd2,
    const float* __restrict__ W1, const float* __restrict__ b1,
    const float* __restrict__ W2, const float* __restrict__ b2,
    float* __restrict__ logits_out)
{
    __shared__ float sW1[64][64];
    __shared__ float sW2[64][32];
    __shared__ float sh[4][64];
    __shared__ float st[4][64];
    const int tid = threadIdx.x;
    for (int i = tid; i < 4096; i += 256) sW1[i >> 6][i & 63] = W1[i];
    for (int i = tid; i < 2048; i += 256) sW2[i >> 5][i & 31] = W2[i];
    const int n0 = blockIdx.x * 4;
    (&sh[0][0])[tid] = hd2[(long)n0 * 64 + tid];
    __syncthreads();
    const int o = tid & 63, dl = tid >> 6;
    float acc = b1[o];
    #pragma unroll 8
    for (int k = 0; k < 64; ++k) acc += sh[dl][k] * sW1[k][o];
    st[dl][o] = fmaxf(acc, 0.f);
    __syncthreads();
    if (tid < 128) {
        int j = tid & 31, d2 = tid >> 5;
        float a2 = b2[j];
        #pragma unroll 8
        for (int k = 0; k < 64; ++k) a2 += st[d2][k] * sW2[k][j];
        logits_out[(long)(n0 + d2) * 32 + j] = a2;
    }
}

// ---------------------------------------------------------------------------
// Softmax stats per (a,t) column: max, first-argmax, sum(exp(x-max)).
// ---------------------------------------------------------------------------
__global__ __launch_bounds__(256) void softmax_stats_kernel(
    const float* __restrict__ logits,
    float* __restrict__ smax, int* __restrict__ sargm, float* __restrict__ ssum)
{
    __shared__ float smx[256];
    __shared__ int sid[256];
    __shared__ float ssm[256];
    const int j = blockIdx.x;
    const int tid = threadIdx.x;
    float best = -__builtin_inff(); int bid = 0x7fffffff;
    for (int n = tid; n < NDEV; n += 256) {
        float v = logits[n * 32 + j];
        if (v > best) { best = v; bid = n; }
    }
    smx[tid] = best; sid[tid] = bid;
    __syncthreads();
    for (int s = 128; s > 0; s >>= 1) {
        if (tid < s) {
            float v2 = smx[tid + s]; int i2 = sid[tid + s];
            if (v2 > smx[tid] || (v2 == smx[tid] && i2 < sid[tid])) { smx[tid] = v2; sid[tid] = i2; }
        }
        __syncthreads();
    }
    const float mx = smx[0];
    float part = 0.f;
    for (int n = tid; n < NDEV; n += 256) part += expf(logits[n * 32 + j] - mx);
    ssm[tid] = part;
    __syncthreads();
    for (int s = 128; s > 0; s >>= 1) {
        if (tid < s) ssm[tid] += ssm[tid + s];
        __syncthreads();
    }
    if (tid == 0) { smax[j] = mx; sargm[j] = sid[0]; ssum[j] = ssm[0]; }
}

__global__ __launch_bounds__(256) void final_kernel(
    const float* __restrict__ logits, const float* __restrict__ smax,
    const int* __restrict__ sargm, const float* __restrict__ ssum,
    float* __restrict__ hard, float* __restrict__ soft)
{
    const int gid = blockIdx.x * 256 + threadIdx.x;
    const int n = gid >> 3, t = gid & 7;
    float s = 0.f; int h = 0;
    #pragma unroll
    for (int a = 0; a < 4; ++a) {
        int j = t * 4 + a;
        s += expf(logits[n * 32 + j] - smax[j]) / ssum[j];
        h |= (sargm[j] == n) ? 1 : 0;
    }
    hard[gid] = (float)h;
    soft[gid] = s;
}

// ---------------------------------------------------------------------------
extern "C" void kernel_launch(void* const* d_in, const int* in_sizes, int n_in,
                              void* d_out, int out_size, void* d_ws, size_t ws_size,
                              hipStream_t stream)
{
    const float* device_pos = (const float*)d_in[0];
    const float* ap_pos     = (const float*)d_in[1];
    const float* csi        = (const float*)d_in[2];
    const int*   node_pk    = (const int*)d_in[3];
    const int* dd_src = (const int*)d_in[4];
    const int* dd_dst = (const int*)d_in[5];
    const int* da_src = (const int*)d_in[6];
    const int* da_dst = (const int*)d_in[7];
    const int* ad_src = (const int*)d_in[8];
    const int* ad_dst = (const int*)d_in[9];
    const float* w1  = (const float*)d_in[10]; const float* b1  = (const float*)d_in[11];
    const float* w2  = (const float*)d_in[12]; const float* b2  = (const float*)d_in[13];
    const float* fcW = (const float*)d_in[14]; const float* fcb = (const float*)d_in[15];
    const float* Wp  = (const float*)d_in[16]; const float* bp  = (const float*)d_in[17];
    const float* Wc  = (const float*)d_in[18]; const float* bc  = (const float*)d_in[19];
    const float* Wm  = (const float*)d_in[20]; const float* bm  = (const float*)d_in[21];
    const float* Wap = (const float*)d_in[22]; const float* bap = (const float*)d_in[23];
    const float* g1ddW = (const float*)d_in[24]; const float* g1ddb = (const float*)d_in[25];
    const float* g1daW = (const float*)d_in[26]; const float* g1dab = (const float*)d_in[27];
    const float* g1adW = (const float*)d_in[28]; const float* g1adb = (const float*)d_in[29];
    const float* g2ddW = (const float*)d_in[30]; const float* g2ddb = (const float*)d_in[31];
    const float* g2adW = (const float*)d_in[34]; const float* g2adb = (const float*)d_in[35];
    const float* a1W = (const float*)d_in[36]; const float* a1b = (const float*)d_in[37];
    const float* a2W = (const float*)d_in[38]; const float* a2b = (const float*)d_in[39];

    float* ws = (float*)d_ws;
    // ws layout (4-byte units)
    size_t o_c2    = 0;                               // 16,777,216
    size_t o_emb   = o_c2 + (size_t)CHUNK * 2048;
    size_t o_hdev  = o_emb + (size_t)NSAMP * 64;
    size_t o_hap   = o_hdev + (size_t)NDEV * 64;      // 256
    size_t o_hd1   = o_hap + 256;
    size_t o_ha1   = o_hd1 + (size_t)NDEV * 64;       // 256
    size_t o_hd2   = o_ha1 + 256;
    size_t o_aggdd = o_hd2 + (size_t)NDEV * 64;
    size_t o_aggad = o_aggdd + (size_t)NDEV * 64;
    // zero region
    size_t o_zero  = o_aggad + (size_t)NDEV * 64;
    size_t o_degddo = o_zero;                 // int[8192]
    size_t o_degddi = o_degddo + NDEV;        // int[8192]
    size_t o_degdao = o_degddi + NDEV;        // int[8192]
    size_t o_degadi = o_degdao + NDEV;        // int[8192]
    size_t o_degsm  = o_degadi + NDEV;        // int[16]
    size_t o_aggda  = o_degsm + 16;           // float[256]
    size_t o_zend   = o_aggda + 256;
    // non-zeroed
    size_t o_rsdd  = o_zend;                  // int[8192]
    size_t o_curdd = o_rsdd + NDEV;
    size_t o_rsad  = o_curdd + NDEV;
    size_t o_curad = o_rsad + NDEV;
    size_t o_ssdd  = o_curad + NDEV;          // int[262144]
    size_t o_ssad  = o_ssdd + EDD;            // int[32768]
    size_t o_smax  = o_ssad + EAD;            // 32
    size_t o_ssum  = o_smax + 32;
    size_t o_sargm = o_ssum + 32;

    float* out = (float*)d_out;
    float* out_hard   = out;                 // [8192][8]
    float* out_logits = out + 65536;         // [8192][32]
    float* out_soft   = out + 65536 + 262144;

    hipMemsetAsync((void*)(ws + o_zero), 0, (o_zend - o_zero) * sizeof(float), stream);

    for (int c = 0; c < 4; ++c) {
        const float* csi_c = csi + (size_t)c * CHUNK * 128;
        float* emb_c = ws + o_emb + (size_t)c * CHUNK * 64;
        conv_kernel<<<CHUNK / 4, 256, 0, stream>>>(csi_c, ws + o_c2, w1, b1, w2, b2);
        fc16_kernel<<<CHUNK / 16, 256, 0, stream>>>(ws + o_c2, fcW, fcb, emb_c);
    }

    dev_enc_kernel<<<NDEV / 8, 256, 0, stream>>>(device_pos, node_pk, ws + o_emb,
                                                 Wp, bp, Wc, bc, Wm, bm, ws + o_hdev);
    ap_enc_kernel<<<1, 256, 0, stream>>>(ap_pos, Wap, bap, ws + o_hap);

    degrees_kernel<<<EDD / 256, 256, 0, stream>>>(dd_src, dd_dst, da_src, da_dst, ad_src, ad_dst,
                                                  (int*)(ws + o_degddo), (int*)(ws + o_degddi),
                                                  (int*)(ws + o_degdao), (int*)(ws + o_degadi),
                                                  (int*)(ws + o_degsm));
    scan_kernel<<<2, 1024, 0, stream>>>((int*)(ws + o_degddi), (int*)(ws + o_rsdd), (int*)(ws + o_curdd),
                                        (int*)(ws + o_degadi), (int*)(ws + o_rsad), (int*)(ws + o_curad));
    reorder_kernel<<<EDD / 256, 256, 0, stream>>>(dd_src, dd_dst, (int*)(ws + o_curdd),
                                                  (int*)(ws + o_ssdd), EDD);
    reorder_kernel<<<EAD / 256, 256, 0, stream>>>(ad_src, ad_dst, (int*)(ws + o_curad),
                                                  (int*)(ws + o_ssad), EAD);

    // layer 1
    gather_kernel<<<NDEV, 256, 0, stream>>>((int*)(ws + o_rsdd), (int*)(ws + o_degddi),
                                            (int*)(ws + o_ssdd), ws + o_hdev,
                                            (int*)(ws + o_degddo), ws + o_aggdd);
    gather_kernel<<<NDEV, 256, 0, stream>>>((int*)(ws + o_rsad), (int*)(ws + o_degadi),
                                            (int*)(ws + o_ssad), ws + o_hap,
                                            (int*)(ws + o_degsm) + 8, ws + o_aggad);
    da_reduce_kernel<<<EDA / 128, 256, 0, stream>>>(da_src, da_dst, ws + o_hdev,
                                                    (int*)(ws + o_degdao), ws + o_aggda);
    combine_hd_kernel<<<NDEV / 4, 256, 0, stream>>>(ws + o_aggdd, g1ddW, g1ddb,
                                                    ws + o_aggad, g1adW, g1adb, ws + o_hd1);
    combine_ha_kernel<<<1, 256, 0, stream>>>(ws + o_aggda, (int*)(ws + o_degsm),
                                             g1daW, g1dab, ws + o_ha1);

    // layer 2
    gather_kernel<<<NDEV, 256, 0, stream>>>((int*)(ws + o_rsdd), (int*)(ws + o_degddi),
                                            (int*)(ws + o_ssdd), ws + o_hd1,
                                            (int*)(ws + o_degddo), ws + o_aggdd);
    gather_kernel<<<NDEV, 256, 0, stream>>>((int*)(ws + o_rsad), (int*)(ws + o_degadi),
                                            (int*)(ws + o_ssad), ws + o_ha1,
                                            (int*)(ws + o_degsm) + 8, ws + o_aggad);
    combine_hd_kernel<<<NDEV / 4, 256, 0, stream>>>(ws + o_aggdd, g2ddW, g2ddb,
                                                    ws + o_aggad, g2adW, g2adb, ws + o_hd2);

    head_kernel<<<NDEV / 4, 256, 0, stream>>>(ws + o_hd2, a1W, a1b, a2W, a2b, out_logits);

    softmax_stats_kernel<<<32, 256, 0, stream>>>(out_logits, ws + o_smax,
                                                 (int*)(ws + o_sargm), ws + o_ssum);
    final_kernel<<<65536 / 256, 256, 0, stream>>>(out_logits, ws + o_smax,
                                                  (int*)(ws + o_sargm), ws + o_ssum,
                                                  out_hard, out_soft);
    (void)in_sizes; (void)n_in; (void)out_size; (void)ws_size;
}

// Round 3
// 864.909 us; speedup vs baseline: 1.6128x; 1.1795x over previous
//
#include <hip/hip_runtime.h>

#define NDEV 8192
#define NAP  4
#define NSAMP 32768
#define EDD 262144
#define EDA 32768
#define EAD 32768
#define CHUNK 8192
#define KC 128

// ---------------------------------------------------------------------------
// Repack conv2 weights [oc][ic][3][3] -> [ic][oc][9] so each wave's 8-oc slab
// is contiguous (wave-uniform s_load in conv_kernel).
// ---------------------------------------------------------------------------
__global__ void repack_w2_kernel(const float* __restrict__ w2, float* __restrict__ wq)
{
    int i = blockIdx.x * 256 + threadIdx.x;
    if (i < 4608) {
        int k = i % 9; int rest = i / 9; int oc = rest & 31; int ic = rest >> 5;
        wq[i] = w2[oc * 144 + ic * 9 + k];
    }
}

// ---------------------------------------------------------------------------
// CSI encoder stage 1: conv1 (2->16) + conv2 (16->32), 3x3 SAME, relu.
// Block = 4 samples, 256 threads. conv2: wave w -> ocs [8w,8w+8);
// lane = 32 rowpos (4si x 8f) x 2 t-halves; weights via wave-uniform s_load.
// ---------------------------------------------------------------------------
__global__ __launch_bounds__(256) void conv_kernel(
    const float* __restrict__ csi,
    float* __restrict__ c2,          // [CHUNK][2048]  (oc*64 + f*8 + t)
    const float* __restrict__ w1, const float* __restrict__ b1,
    const float* __restrict__ wq,    // [16][32][9] repacked
    const float* __restrict__ b2)
{
    __shared__ float sw1[288];
    __shared__ float sb1[16];
    __shared__ float sb2[32];
    __shared__ float inpad[4][2][10][10];        // 800
    __shared__ float c1pad[4][16][10][12];       // 7680, row stride 12 (16B-aligned rows)
    const int tid = threadIdx.x;

    for (int i = tid; i < 288; i += 256) sw1[i] = w1[i];
    if (tid < 16) sb1[tid] = b1[tid];
    if (tid < 32) sb2[tid] = b2[tid];
    float* ip = &inpad[0][0][0][0];
    for (int i = tid; i < 800; i += 256) ip[i] = 0.f;
    float* cp = &c1pad[0][0][0][0];
    for (int i = tid; i < 7680; i += 256) cp[i] = 0.f;
    __syncthreads();

    const long s0 = (long)blockIdx.x * 4;
    for (int i = tid; i < 512; i += 256) {
        int si = i >> 7, r = i & 127;
        int f = r >> 4, t = (r >> 1) & 7, c = r & 1;
        inpad[si][c][f + 1][t + 1] = csi[s0 * 128 + i];
    }
    __syncthreads();

    // conv1: 4096 outputs, 16 per thread
    for (int j = 0; j < 16; ++j) {
        int idx = tid + j * 256;
        int t = idx & 7, f = (idx >> 3) & 7, oc = (idx >> 6) & 15, si = idx >> 10;
        float acc = sb1[oc];
        #pragma unroll
        for (int ic = 0; ic < 2; ++ic)
            #pragma unroll
            for (int df = 0; df < 3; ++df)
                #pragma unroll
                for (int dt = 0; dt < 3; ++dt)
                    acc += inpad[si][ic][f + df][t + dt] * sw1[((oc * 2 + ic) * 3 + df) * 3 + dt];
        c1pad[si][oc][f + 1][t + 1] = fmaxf(acc, 0.f);
    }
    __syncthreads();

    // conv2
    const int wv = __builtin_amdgcn_readfirstlane(tid >> 6);   // wave id: ocs wv*8..wv*8+7
    const int lane = tid & 63;
    const int pos = lane & 31;
    const int si = pos >> 3, fr = pos & 7;
    const int th = lane >> 5, tb = th * 4;

    float acc[8][4];
    #pragma unroll
    for (int i = 0; i < 8; ++i)
        #pragma unroll
        for (int j = 0; j < 4; ++j) acc[i][j] = 0.f;

    for (int ic = 0; ic < 16; ++ic) {
        float rr[3][6];
        #pragma unroll
        for (int r = 0; r < 3; ++r) {
            float4 a = *(const float4*)&c1pad[si][ic][fr + r][tb];
            float2 b = *(const float2*)&c1pad[si][ic][fr + r][tb + 4];
            rr[r][0] = a.x; rr[r][1] = a.y; rr[r][2] = a.z; rr[r][3] = a.w;
            rr[r][4] = b.x; rr[r][5] = b.y;
        }
        #pragma unroll
        for (int ocp = 0; ocp < 2; ++ocp) {
            const float* wp = wq + (size_t)(ic * 32 + wv * 8 + ocp * 4) * 9;
            float w[36];
            #pragma unroll
            for (int k = 0; k < 36; ++k) w[k] = wp[k];
            #pragma unroll
            for (int i = 0; i < 4; ++i)
                #pragma unroll
                for (int df = 0; df < 3; ++df)
                    #pragma unroll
                    for (int dt = 0; dt < 3; ++dt) {
                        float wv_ = w[i * 9 + df * 3 + dt];
                        #pragma unroll
                        for (int j = 0; j < 4; ++j)
                            acc[ocp * 4 + i][j] += rr[df][j + dt] * wv_;
                    }
        }
    }
    #pragma unroll
    for (int i = 0; i < 8; ++i) {
        int oc = wv * 8 + i;
        float b = sb2[oc];
        float4 o4;
        o4.x = fmaxf(acc[i][0] + b, 0.f);
        o4.y = fmaxf(acc[i][1] + b, 0.f);
        o4.z = fmaxf(acc[i][2] + b, 0.f);
        o4.w = fmaxf(acc[i][3] + b, 0.f);
        *(float4*)&c2[(s0 + si) * 2048 + oc * 64 + fr * 8 + tb] = o4;
    }
}

// ---------------------------------------------------------------------------
// CSI encoder stage 2: [CHUNK,2048] @ [2048,64] + bias, relu.
// ---------------------------------------------------------------------------
__global__ __launch_bounds__(256) void fc16_kernel(
    const float* __restrict__ c2, const float* __restrict__ W,
    const float* __restrict__ bias, float* __restrict__ out)
{
    __shared__ __align__(16) float smem[KC * 16 + KC * 64];
    float* As = smem;
    float* Ws = smem + KC * 16;
    const int tid = threadIdx.x;
    const long m0g = (long)blockIdx.x * 16;
    const int ks = tid >> 6;
    const int lane = tid & 63;
    const int m0 = (lane >> 4) * 4;
    const int o0 = (lane & 15) * 4;
    float acc[4][4] = {{0.f}};

    for (int kc = 0; kc < 2048; kc += KC) {
        __syncthreads();
        #pragma unroll
        for (int i = 0; i < 2; ++i) {
            int idx = tid + i * 256;
            int m = idx >> 5, kq = idx & 31;
            float4 v = *(const float4*)&c2[(m0g + m) * 2048 + kc + kq * 4];
            As[(kq * 4 + 0) * 16 + m] = v.x;
            As[(kq * 4 + 1) * 16 + m] = v.y;
            As[(kq * 4 + 2) * 16 + m] = v.z;
            As[(kq * 4 + 3) * 16 + m] = v.w;
        }
        #pragma unroll
        for (int i = 0; i < 8; ++i) {
            int idx = tid + i * 256;
            int k = idx >> 4, oq = idx & 15;
            *(float4*)&Ws[k * 64 + oq * 4] = *(const float4*)&W[(long)(kc + k) * 64 + oq * 4];
        }
        __syncthreads();
        const int kb = ks * 32;
        #pragma unroll 8
        for (int kk = 0; kk < 32; ++kk) {
            float4 a4 = *(const float4*)&As[(kb + kk) * 16 + m0];
            float4 w4 = *(const float4*)&Ws[(kb + kk) * 64 + o0];
            float av[4] = {a4.x, a4.y, a4.z, a4.w};
            float wv[4] = {w4.x, w4.y, w4.z, w4.w};
            #pragma unroll
            for (int i = 0; i < 4; ++i)
                #pragma unroll
                for (int j = 0; j < 4; ++j)
                    acc[i][j] += av[i] * wv[j];
        }
    }
    __syncthreads();
    float* red = smem;
    #pragma unroll
    for (int i = 0; i < 4; ++i)
        #pragma unroll
        for (int j = 0; j < 4; ++j)
            red[(ks * 16 + m0 + i) * 64 + o0 + j] = acc[i][j];
    __syncthreads();
    {
        int m = tid >> 4, oq = tid & 15;
        float4 r0 = *(float4*)&red[(0 * 16 + m) * 64 + oq * 4];
        float4 r1 = *(float4*)&red[(1 * 16 + m) * 64 + oq * 4];
        float4 r2 = *(float4*)&red[(2 * 16 + m) * 64 + oq * 4];
        float4 r3 = *(float4*)&red[(3 * 16 + m) * 64 + oq * 4];
        const float4 b4 = *(const float4*)&bias[oq * 4];
        float4 o4;
        o4.x = fmaxf(r0.x + r1.x + r2.x + r3.x + b4.x, 0.f);
        o4.y = fmaxf(r0.y + r1.y + r2.y + r3.y + b4.y, 0.f);
        o4.z = fmaxf(r0.z + r1.z + r2.z + r3.z + b4.z, 0.f);
        o4.w = fmaxf(r0.w + r1.w + r2.w + r3.w + b4.w, 0.f);
        *(float4*)&out[(m0g + m) * 64 + oq * 4] = o4;
    }
}

// ---------------------------------------------------------------------------
__global__ __launch_bounds__(256) void dev_enc_kernel(
    const float* __restrict__ dpos, const int* __restrict__ pkts,
    const float* __restrict__ emb,
    const float* __restrict__ Wp, const float* __restrict__ bp,
    const float* __restrict__ Wc, const float* __restrict__ bc,
    const float* __restrict__ Wm, const float* __restrict__ bm,
    float* __restrict__ hdev)
{
    __shared__ float se[8][256];
    __shared__ float sposf[8][16];
    __shared__ float scsif[8][64];
    const int tid = threadIdx.x;
    const int d0 = blockIdx.x * 8;
    for (int i = tid; i < 2048; i += 256) se[i >> 8][i & 255] = emb[(long)d0 * 256 + i];
    __syncthreads();
    const int o = tid & 63, g = tid >> 6;
    for (int half = 0; half < 2; ++half) {
        int dl = half * 4 + g;
        float a = bc[o];
        for (int k = 0; k < 256; ++k) a += se[dl][k] * Wc[k * 64 + o];
        scsif[dl][o] = fmaxf(a, 0.f);
        if (o < 16) {
            int d = d0 + dl;
            float px = dpos[d * 2], py = dpos[d * 2 + 1], pk = (float)pkts[d];
            float v = bp[o] + px * Wp[o] + py * Wp[16 + o] + pk * Wp[32 + o];
            sposf[dl][o] = fmaxf(v, 0.f);
        }
    }
    __syncthreads();
    for (int half = 0; half < 2; ++half) {
        int dl = half * 4 + g;
        float h = bm[o];
        #pragma unroll
        for (int j = 0; j < 16; ++j) h += sposf[dl][j] * Wm[j * 64 + o];
        #pragma unroll 8
        for (int j = 0; j < 64; ++j) h += scsif[dl][j] * Wm[(16 + j) * 64 + o];
        hdev[(long)(d0 + dl) * 64 + o] = fmaxf(h, 0.f);
    }
}

__global__ void ap_enc_kernel(const float* __restrict__ appos,
                              const float* __restrict__ W, const float* __restrict__ b,
                              float* __restrict__ hap)
{
    int tid = threadIdx.x;
    int a = tid >> 6, o = tid & 63;
    float v = b[o] + appos[a * 2] * W[o] + appos[a * 2 + 1] * W[64 + o];
    hap[tid] = fmaxf(v, 0.f);
}

// ---------------------------------------------------------------------------
__global__ __launch_bounds__(256) void degrees_kernel(
    const int* __restrict__ dd_src, const int* __restrict__ dd_dst,
    const int* __restrict__ da_src, const int* __restrict__ da_dst,
    const int* __restrict__ ad_src, const int* __restrict__ ad_dst,
    int* deg_dd_out, int* deg_dd_in, int* deg_da_out, int* deg_ad_in, int* deg_small)
{
    __shared__ int s4[16];
    const int tid = threadIdx.x;
    if (tid < 16) s4[tid] = 0;
    __syncthreads();
    const int gid = blockIdx.x * 256 + tid;
    atomicAdd(&deg_dd_out[dd_src[gid]], 1);
    atomicAdd(&deg_dd_in[dd_dst[gid]], 1);
    if (gid < EDA) {
        atomicAdd(&deg_da_out[da_src[gid]], 1);
        atomicAdd(&s4[da_dst[gid]], 1);
        atomicAdd(&s4[8 + ad_src[gid]], 1);
        atomicAdd(&deg_ad_in[ad_dst[gid]], 1);
    }
    __syncthreads();
    if (tid < 16 && s4[tid] != 0) atomicAdd(&deg_small[tid], s4[tid]);
}

__global__ __launch_bounds__(1024) void scan_kernel(
    const int* __restrict__ degA, int* rsA, int* curA,
    const int* __restrict__ degB, int* rsB, int* curB)
{
    const int* deg = blockIdx.x ? degB : degA;
    int* rs = blockIdx.x ? rsB : rsA;
    int* cur = blockIdx.x ? curB : curA;
    __shared__ int sd[1024];
    const int tid = threadIdx.x;
    const int base = tid * 8;
    int v[8]; int s = 0;
    #pragma unroll
    for (int j = 0; j < 8; ++j) { v[j] = deg[base + j]; s += v[j]; }
    sd[tid] = s;
    __syncthreads();
    for (int off = 1; off < 1024; off <<= 1) {
        int t = (tid >= off) ? sd[tid - off] : 0;
        __syncthreads();
        sd[tid] += t;
        __syncthreads();
    }
    int ex = sd[tid] - s;
    #pragma unroll
    for (int j = 0; j < 8; ++j) { rs[base + j] = ex; cur[base + j] = ex; ex += v[j]; }
}

__global__ __launch_bounds__(256) void reorder_kernel(
    const int* __restrict__ src, const int* __restrict__ dst,
    int* __restrict__ cursor, int* __restrict__ ssrc, int nE)
{
    int e = blockIdx.x * 256 + threadIdx.x;
    if (e < nE) {
        int pos = atomicAdd(&cursor[dst[e]], 1);
        ssrc[pos] = src[e];
    }
}

// ---------------------------------------------------------------------------
// Pre-normalize x by rsqrt(deg_out) so gather is a pure gather-add.
// ---------------------------------------------------------------------------
__global__ __launch_bounds__(256) void xnorm_kernel(
    const float* __restrict__ x, const int* __restrict__ deg, float* __restrict__ xn)
{
    int gid = blockIdx.x * 256 + threadIdx.x;
    xn[gid] = x[gid] * rsqrtf(fmaxf((float)deg[gid >> 6], 1.f));
}

__global__ void xnorm_ap_kernel(
    const float* __restrict__ x, const int* __restrict__ deg, float* __restrict__ xn)
{
    int tid = threadIdx.x;  // 256
    xn[tid] = x[tid] * rsqrtf(fmaxf((float)deg[tid >> 6], 1.f));
}

// ---------------------------------------------------------------------------
// CSR gather: one wave per dst (4 dsts/block). agg[d] = rsqrt(deg_in)*sum xn[src].
// ---------------------------------------------------------------------------
__global__ __launch_bounds__(256) void gather_kernel(
    const int* __restrict__ row_start, const int* __restrict__ deg_in,
    const int* __restrict__ ssrc, const float* __restrict__ xn,
    float* __restrict__ agg)
{
    const int tid = threadIdx.x;
    const int w = __builtin_amdgcn_readfirstlane(tid >> 6);
    const int f = tid & 63;
    const int d = blockIdx.x * 4 + w;
    const int start = row_start[d], len = deg_in[d];
    float acc = 0.f;
    int j = 0;
    for (; j + 4 <= len; j += 4) {
        int s0 = ssrc[start + j], s1 = ssrc[start + j + 1];
        int s2 = ssrc[start + j + 2], s3 = ssrc[start + j + 3];
        float v0 = xn[(long)s0 * 64 + f], v1 = xn[(long)s1 * 64 + f];
        float v2 = xn[(long)s2 * 64 + f], v3 = xn[(long)s3 * 64 + f];
        acc += (v0 + v1) + (v2 + v3);
    }
    for (; j < len; ++j) acc += xn[(long)ssrc[start + j] * 64 + f];
    agg[(long)d * 64 + f] = acc * rsqrtf(fmaxf((float)len, 1.f));
}

// da relation: 4 dsts, LDS block reduction then global atomics.
__global__ __launch_bounds__(256) void da_reduce_kernel(
    const int* __restrict__ src, const int* __restrict__ dst,
    const float* __restrict__ x, const int* __restrict__ deg_out,
    float* __restrict__ agg /* [4][64] */)
{
    __shared__ float sacc[4][64];
    const int tid = threadIdx.x;
    (&sacc[0][0])[tid] = 0.f;
    __syncthreads();
    const int f = tid & 63;
    const int base = blockIdx.x * 128;
    for (int e = base + (tid >> 6); e < base + 128; e += 4) {
        int s = src[e], d = dst[e];
        float sc = rsqrtf(fmaxf((float)deg_out[s], 1.f));
        atomicAdd(&sacc[d][f], x[(long)s * 64 + f] * sc);
    }
    __syncthreads();
    float v = (&sacc[0][0])[tid];
    if (v != 0.f) atomicAdd(&agg[tid], v);
}

// ---------------------------------------------------------------------------
__global__ __launch_bounds__(256) void combine_hd_kernel(
    const float* __restrict__ agg1, const float* __restrict__ W1, const float* __restrict__ b1,
    const float* __restrict__ agg2, const float* __restrict__ W2, const float* __restrict__ b2,
    float* __restrict__ out)
{
    __shared__ float sW1[64][64];
    __shared__ float sW2[64][64];
    __shared__ float sa1[4][64];
    __shared__ float sa2[4][64];
    const int tid = threadIdx.x;
    for (int i = tid; i < 4096; i += 256) { sW1[i >> 6][i & 63] = W1[i]; sW2[i >> 6][i & 63] = W2[i]; }
    const int n0 = blockIdx.x * 4;
    (&sa1[0][0])[tid] = agg1[(long)n0 * 64 + tid];
    (&sa2[0][0])[tid] = agg2[(long)n0 * 64 + tid];
    __syncthreads();
    const int o = tid & 63, dl = tid >> 6;
    float acc1 = 0.f, acc2 = 0.f;
    #pragma unroll 8
    for (int k = 0; k < 64; ++k) {
        acc1 += sa1[dl][k] * sW1[k][o];
        acc2 += sa2[dl][k] * sW2[k][o];
    }
    out[(long)(n0 + dl) * 64 + o] = fmaxf(acc1 + acc2 + b1[o] + b2[o], 0.f);
}

__global__ void combine_ha_kernel(const float* __restrict__ agg, const int* __restrict__ degin,
                                  const float* __restrict__ W, const float* __restrict__ b,
                                  float* __restrict__ out)
{
    const int tid = threadIdx.x;
    const int o = tid & 63, a = tid >> 6;
    float acc = 0.f;
    for (int k = 0; k < 64; ++k) acc += agg[a * 64 + k] * W[k * 64 + o];
    float r = rsqrtf(fmaxf((float)degin[a], 1.f));
    out[tid] = fmaxf(acc * r + b[o], 0.f);
}

// ---------------------------------------------------------------------------
__global__ __launch_bounds__(256) void head_kernel(
    const float* __restrict__ hd2,
    const float* __restrict__ W1, const float* __restrict__ b1,
    const float* __restrict__ W2, const float* __restrict__ b2,
    float* __restrict__ logits_out)
{
    __shared__ float sW1[64][64];
    __shared__ float sW2[64][32];
    __shared__ float sh[4][64];
    __shared__ float st[4][64];
    const int tid = threadIdx.x;
    for (int i = tid; i < 4096; i += 256) sW1[i >> 6][i & 63] = W1[i];
    for (int i = tid; i < 2048; i += 256) sW2[i >> 5][i & 31] = W2[i];
    const int n0 = blockIdx.x * 4;
    (&sh[0][0])[tid] = hd2[(long)n0 * 64 + tid];
    __syncthreads();
    const int o = tid & 63, dl = tid >> 6;
    float acc = b1[o];
    #pragma unroll 8
    for (int k = 0; k < 64; ++k) acc += sh[dl][k] * sW1[k][o];
    st[dl][o] = fmaxf(acc, 0.f);
    __syncthreads();
    if (tid < 128) {
        int j = tid & 31, d2 = tid >> 5;
        float a2 = b2[j];
        #pragma unroll 8
        for (int k = 0; k < 64; ++k) a2 += st[d2][k] * sW2[k][j];
        logits_out[(long)(n0 + d2) * 32 + j] = a2;
    }
}

// ---------------------------------------------------------------------------
__global__ __launch_bounds__(256) void softmax_stats_kernel(
    const float* __restrict__ logits,
    float* __restrict__ smax, int* __restrict__ sargm, float* __restrict__ ssum)
{
    __shared__ float smx[256];
    __shared__ int sid[256];
    __shared__ float ssm[256];
    const int j = blockIdx.x;
    const int tid = threadIdx.x;
    float best = -__builtin_inff(); int bid = 0x7fffffff;
    for (int n = tid; n < NDEV; n += 256) {
        float v = logits[n * 32 + j];
        if (v > best) { best = v; bid = n; }
    }
    smx[tid] = best; sid[tid] = bid;
    __syncthreads();
    for (int s = 128; s > 0; s >>= 1) {
        if (tid < s) {
            float v2 = smx[tid + s]; int i2 = sid[tid + s];
            if (v2 > smx[tid] || (v2 == smx[tid] && i2 < sid[tid])) { smx[tid] = v2; sid[tid] = i2; }
        }
        __syncthreads();
    }
    const float mx = smx[0];
    float part = 0.f;
    for (int n = tid; n < NDEV; n += 256) part += expf(logits[n * 32 + j] - mx);
    ssm[tid] = part;
    __syncthreads();
    for (int s = 128; s > 0; s >>= 1) {
        if (tid < s) ssm[tid] += ssm[tid + s];
        __syncthreads();
    }
    if (tid == 0) { smax[j] = mx; sargm[j] = sid[0]; ssum[j] = ssm[0]; }
}

__global__ __launch_bounds__(256) void final_kernel(
    const float* __restrict__ logits, const float* __restrict__ smax,
    const int* __restrict__ sargm, const float* __restrict__ ssum,
    float* __restrict__ hard, float* __restrict__ soft)
{
    const int gid = blockIdx.x * 256 + threadIdx.x;
    const int n = gid >> 3, t = gid & 7;
    float s = 0.f; int h = 0;
    #pragma unroll
    for (int a = 0; a < 4; ++a) {
        int j = t * 4 + a;
        s += expf(logits[n * 32 + j] - smax[j]) / ssum[j];
        h |= (sargm[j] == n) ? 1 : 0;
    }
    hard[gid] = (float)h;
    soft[gid] = s;
}

// ---------------------------------------------------------------------------
extern "C" void kernel_launch(void* const* d_in, const int* in_sizes, int n_in,
                              void* d_out, int out_size, void* d_ws, size_t ws_size,
                              hipStream_t stream)
{
    const float* device_pos = (const float*)d_in[0];
    const float* ap_pos     = (const float*)d_in[1];
    const float* csi        = (const float*)d_in[2];
    const int*   node_pk    = (const int*)d_in[3];
    const int* dd_src = (const int*)d_in[4];
    const int* dd_dst = (const int*)d_in[5];
    const int* da_src = (const int*)d_in[6];
    const int* da_dst = (const int*)d_in[7];
    const int* ad_src = (const int*)d_in[8];
    const int* ad_dst = (const int*)d_in[9];
    const float* w1  = (const float*)d_in[10]; const float* b1  = (const float*)d_in[11];
    const float* w2  = (const float*)d_in[12]; const float* b2  = (const float*)d_in[13];
    const float* fcW = (const float*)d_in[14]; const float* fcb = (const float*)d_in[15];
    const float* Wp  = (const float*)d_in[16]; const float* bp  = (const float*)d_in[17];
    const float* Wc  = (const float*)d_in[18]; const float* bc  = (const float*)d_in[19];
    const float* Wm  = (const float*)d_in[20]; const float* bm  = (const float*)d_in[21];
    const float* Wap = (const float*)d_in[22]; const float* bap = (const float*)d_in[23];
    const float* g1ddW = (const float*)d_in[24]; const float* g1ddb = (const float*)d_in[25];
    const float* g1daW = (const float*)d_in[26]; const float* g1dab = (const float*)d_in[27];
    const float* g1adW = (const float*)d_in[28]; const float* g1adb = (const float*)d_in[29];
    const float* g2ddW = (const float*)d_in[30]; const float* g2ddb = (const float*)d_in[31];
    const float* g2adW = (const float*)d_in[34]; const float* g2adb = (const float*)d_in[35];
    const float* a1W = (const float*)d_in[36]; const float* a1b = (const float*)d_in[37];
    const float* a2W = (const float*)d_in[38]; const float* a2b = (const float*)d_in[39];

    float* ws = (float*)d_ws;
    // ws layout (4-byte units)
    size_t o_c2    = 0;                               // 16,777,216
    size_t o_emb   = o_c2 + (size_t)CHUNK * 2048;
    size_t o_hdev  = o_emb + (size_t)NSAMP * 64;
    size_t o_hap   = o_hdev + (size_t)NDEV * 64;      // 256
    size_t o_hd1   = o_hap + 256;
    size_t o_ha1   = o_hd1 + (size_t)NDEV * 64;       // 256
    size_t o_hd2   = o_ha1 + 256;
    size_t o_aggdd = o_hd2 + (size_t)NDEV * 64;
    size_t o_aggad = o_aggdd + (size_t)NDEV * 64;
    size_t o_xn    = o_aggad + (size_t)NDEV * 64;     // prenormalized features
    size_t o_xnap  = o_xn + (size_t)NDEV * 64;        // 256
    size_t o_wq    = o_xnap + 256;                    // 4608
    // zero region
    size_t o_zero  = o_wq + 4608;
    size_t o_degddo = o_zero;                 // int[8192]
    size_t o_degddi = o_degddo + NDEV;
    size_t o_degdao = o_degddi + NDEV;
    size_t o_degadi = o_degdao + NDEV;
    size_t o_degsm  = o_degadi + NDEV;        // int[16]
    size_t o_aggda  = o_degsm + 16;           // float[256]
    size_t o_zend   = o_aggda + 256;
    // non-zeroed
    size_t o_rsdd  = o_zend;
    size_t o_curdd = o_rsdd + NDEV;
    size_t o_rsad  = o_curdd + NDEV;
    size_t o_curad = o_rsad + NDEV;
    size_t o_ssdd  = o_curad + NDEV;          // int[262144]
    size_t o_ssad  = o_ssdd + EDD;            // int[32768]
    size_t o_smax  = o_ssad + EAD;
    size_t o_ssum  = o_smax + 32;
    size_t o_sargm = o_ssum + 32;

    float* out = (float*)d_out;
    float* out_hard   = out;                 // [8192][8]
    float* out_logits = out + 65536;         // [8192][32]
    float* out_soft   = out + 65536 + 262144;

    hipMemsetAsync((void*)(ws + o_zero), 0, (o_zend - o_zero) * sizeof(float), stream);
    repack_w2_kernel<<<18, 256, 0, stream>>>(w2, ws + o_wq);

    for (int c = 0; c < 4; ++c) {
        const float* csi_c = csi + (size_t)c * CHUNK * 128;
        float* emb_c = ws + o_emb + (size_t)c * CHUNK * 64;
        conv_kernel<<<CHUNK / 4, 256, 0, stream>>>(csi_c, ws + o_c2, w1, b1, ws + o_wq, b2);
        fc16_kernel<<<CHUNK / 16, 256, 0, stream>>>(ws + o_c2, fcW, fcb, emb_c);
    }

    dev_enc_kernel<<<NDEV / 8, 256, 0, stream>>>(device_pos, node_pk, ws + o_emb,
                                                 Wp, bp, Wc, bc, Wm, bm, ws + o_hdev);
    ap_enc_kernel<<<1, 256, 0, stream>>>(ap_pos, Wap, bap, ws + o_hap);

    degrees_kernel<<<EDD / 256, 256, 0, stream>>>(dd_src, dd_dst, da_src, da_dst, ad_src, ad_dst,
                                                  (int*)(ws + o_degddo), (int*)(ws + o_degddi),
                                                  (int*)(ws + o_degdao), (int*)(ws + o_degadi),
                                                  (int*)(ws + o_degsm));
    scan_kernel<<<2, 1024, 0, stream>>>((int*)(ws + o_degddi), (int*)(ws + o_rsdd), (int*)(ws + o_curdd),
                                        (int*)(ws + o_degadi), (int*)(ws + o_rsad), (int*)(ws + o_curad));
    reorder_kernel<<<EDD / 256, 256, 0, stream>>>(dd_src, dd_dst, (int*)(ws + o_curdd),
                                                  (int*)(ws + o_ssdd), EDD);
    reorder_kernel<<<EAD / 256, 256, 0, stream>>>(ad_src, ad_dst, (int*)(ws + o_curad),
                                                  (int*)(ws + o_ssad), EAD);

    // layer 1
    xnorm_kernel<<<NDEV * 64 / 256, 256, 0, stream>>>(ws + o_hdev, (int*)(ws + o_degddo), ws + o_xn);
    xnorm_ap_kernel<<<1, 256, 0, stream>>>(ws + o_hap, (int*)(ws + o_degsm) + 8, ws + o_xnap);
    gather_kernel<<<NDEV / 4, 256, 0, stream>>>((int*)(ws + o_rsdd), (int*)(ws + o_degddi),
                                                (int*)(ws + o_ssdd), ws + o_xn, ws + o_aggdd);
    gather_kernel<<<NDEV / 4, 256, 0, stream>>>((int*)(ws + o_rsad), (int*)(ws + o_degadi),
                                                (int*)(ws + o_ssad), ws + o_xnap, ws + o_aggad);
    da_reduce_kernel<<<EDA / 128, 256, 0, stream>>>(da_src, da_dst, ws + o_hdev,
                                                    (int*)(ws + o_degdao), ws + o_aggda);
    combine_hd_kernel<<<NDEV / 4, 256, 0, stream>>>(ws + o_aggdd, g1ddW, g1ddb,
                                                    ws + o_aggad, g1adW, g1adb, ws + o_hd1);
    combine_ha_kernel<<<1, 256, 0, stream>>>(ws + o_aggda, (int*)(ws + o_degsm),
                                             g1daW, g1dab, ws + o_ha1);

    // layer 2
    xnorm_kernel<<<NDEV * 64 / 256, 256, 0, stream>>>(ws + o_hd1, (int*)(ws + o_degddo), ws + o_xn);
    xnorm_ap_kernel<<<1, 256, 0, stream>>>(ws + o_ha1, (int*)(ws + o_degsm) + 8, ws + o_xnap);
    gather_kernel<<<NDEV / 4, 256, 0, stream>>>((int*)(ws + o_rsdd), (int*)(ws + o_degddi),
                                                (int*)(ws + o_ssdd), ws + o_xn, ws + o_aggdd);
    gather_kernel<<<NDEV / 4, 256, 0, stream>>>((int*)(ws + o_rsad), (int*)(ws + o_degadi),
                                                (int*)(ws + o_ssad), ws + o_xnap, ws + o_aggad);
    combine_hd_kernel<<<NDEV / 4, 256, 0, stream>>>(ws + o_aggdd, g2ddW, g2ddb,
                                                    ws + o_aggad, g2adW, g2adb, ws + o_hd2);

    head_kernel<<<NDEV / 4, 256, 0, stream>>>(ws + o_hd2, a1W, a1b, a2W, a2b, out_logits);

    softmax_stats_kernel<<<32, 256, 0, stream>>>(out_logits, ws + o_smax,
                                                 (int*)(ws + o_sargm), ws + o_ssum);
    final_kernel<<<65536 / 256, 256, 0, stream>>>(out_logits, ws + o_smax,
                                                  (int*)(ws + o_sargm), ws + o_ssum,
                                                  out_hard, out_soft);
    (void)in_sizes; (void)n_in; (void)out_size; (void)ws_size;
}